// Round 6
// baseline (154.440 us; speedup 1.0000x reference)
//
#include <hip/hip_runtime.h>

#define BB 32
#define CC 512
#define COO 512
#define HH 56
#define WW 56
#define HW 3136
#define NPOS 100352      // B*H*W
#define EPSF 1e-5f

typedef unsigned long long u64;
typedef unsigned int u32;
typedef unsigned short u16;

// ---------------- workspace layout (bytes) ----------------  total 6,460,928
// s1     : u64[8][NPOS]  = 6,422,528   stage-1 sign bits (word-major)
// wbits  : u64[512*8]    = 32,768      pointwise weight sign bits
// wn     : u64[9*8]      = 576         ~sign(w_dw) per tap per cw
// NT     : u64[3*8*5]    = 960         per-(Nv cat, cw): 4 planes of ~T* + flip
// bn2inv/bn2beta : float[512] each
#define OFF_S1      0
#define OFF_WBITS   6422528
#define OFF_WN      6455296
#define OFF_NT      6455872
#define OFF_BN2INV  6456832
#define OFF_BN2BETA 6458880

__global__ __launch_bounds__(256) void setup_kernel(
    const float* __restrict__ w_dw, const float* __restrict__ w_pw,
    const float* __restrict__ g1, const float* __restrict__ b1,
    const float* __restrict__ m1, const float* __restrict__ v1,
    const float* __restrict__ g2, const float* __restrict__ b2,
    const float* __restrict__ m2, const float* __restrict__ v2,
    u64* __restrict__ wbits, u64* __restrict__ wn, u64* __restrict__ NT,
    float* __restrict__ bn2inv, float* __restrict__ bn2beta) {
    const int t = blockIdx.x * 256 + threadIdx.x;   // 0..4095

    // pointwise weight sign bits (all 4096 threads)
    {
        int o = t >> 3, wi = t & 7;
        const float* wp = w_pw + (size_t)o * CC + wi * 64;
        u64 wrd = 0;
        #pragma unroll 8
        for (int k = 0; k < 64; ++k)
            wrd |= (u64)(wp[k] >= 0.f) << k;
        wbits[t] = wrd;
    }

    if (t < CC) {                       // BN2 affine
        float i2 = g2[t] / sqrtf(v2[t] + EPSF);
        bn2inv[t]  = i2;
        bn2beta[t] = b2[t] - m2[t] * i2;
    } else if (t >= 512 && t < 584) {   // depthwise weight ~sign words
        int q = t - 512, cw = q & 7, tap = q >> 3;   // tap = kh*3+kw
        u64 wv = 0;
        for (int cl = 0; cl < 64; ++cl)
            wv |= (u64)(w_dw[(size_t)(cw * 64 + cl) * 9 + tap] < 0.f) << cl;
        wn[tap * 8 + cw] = wv;
    } else if (t >= 1024 && t < 1048) { // BN1 threshold bitplanes
        int q = t - 1024, cat = q / 8, cw = q % 8;
        const int Nv = (cat == 0) ? 9 : ((cat == 1) ? 6 : 4);
        u64 p0 = 0, p1 = 0, p2 = 0, p3 = 0, F = 0;
        for (int cl = 0; cl < 64; ++cl) {
            int c = cw * 64 + cl;
            float i1 = g1[c] / sqrtf(v1[c] + EPSF);
            float be = b1[c] - m1[c] * i1;
            int T, f;
            if (i1 > 0.f) {
                double h = ((double)Nv - (double)be / (double)i1) * 0.5;
                f = 0;
                if (!(h > 0.0)) T = 0;
                else if (h > 15.0) T = 15;
                else T = (int)ceil(h);
            } else if (i1 < 0.f) {
                double h = ((double)Nv - (double)be / (double)i1) * 0.5;
                f = 1;
                if (h < 0.0) T = 0;
                else if (h >= 15.0) T = 15;
                else { T = (int)floor(h) + 1; if (T > 15) T = 15; }
            } else {
                f = 0;
                T = (be >= 0.f) ? 0 : 15;   // always true / never true (E<=9<15)
            }
            unsigned nt = (~(unsigned)T) & 0xFu;
            p0 |= (u64)(nt & 1) << cl;
            p1 |= (u64)((nt >> 1) & 1) << cl;
            p2 |= (u64)((nt >> 2) & 1) << cl;
            p3 |= (u64)((nt >> 3) & 1) << cl;
            F  |= (u64)f << cl;
        }
        u64* d = NT + (size_t)(cat * 8 + cw) * 5;
        d[0] = p0; d[1] = p1; d[2] = p2; d[3] = p3; d[4] = F;
    }
}

__device__ __forceinline__ void fa(u64 a, u64 b, u64 c, u64& s, u64& cy) {
    u64 ab = a ^ b;
    s  = ab ^ c;
    cy = (ab & c) | (a & b);
}

// Fused: binarize(x) -> LDS bitpack -> depthwise 3x3 + BN1 + sign (bit-domain) -> s1
// grid (strip=4, cw=8, b=32) x 512; strip covers 14 output rows (+2 halo rows in LDS)
__global__ __launch_bounds__(512) void dwfused_kernel(
    const float* __restrict__ x, const u64* __restrict__ wn,
    const u64* __restrict__ NT, u64* __restrict__ s1) {
    __shared__ u64 xb[16 * 56];          // rows r0-1 .. r0+14, 7168 B
    const int strip = blockIdx.x;
    const int cw    = blockIdx.y;
    const int b     = blockIdx.z;
    const int tid   = threadIdx.x;
    const int r0    = strip * 14;

    const float* xc = x + ((size_t)b * CC + cw * 64) * HW;
    u16* xb16 = (u16*)xb;

    // ---- pack phase: 896 tasks = 16 lds-rows x 14 colgroups x 4 channel-slices
    for (int tau = tid; tau < 896; tau += 512) {
        const int lrow   = tau / 56;
        const int rest   = tau - lrow * 56;
        const int colgrp = rest >> 2, cg = rest & 3;
        const int h      = r0 - 1 + lrow;
        const int col0   = colgrp * 4;
        u16 o0 = 0, o1 = 0, o2 = 0, o3 = 0;
        if (h >= 0 && h < HH) {
            const float* bp = xc + (size_t)(cg * 16) * HW + h * WW + col0;
            u32 a0 = 0, a1 = 0, a2 = 0, a3 = 0;
            #pragma unroll
            for (int cl = 0; cl < 16; ++cl) {
                float4 v = *(const float4*)(bp + (size_t)cl * HW);
                a0 |= (__float_as_uint(v.x) >> 31) << cl;
                a1 |= (__float_as_uint(v.y) >> 31) << cl;
                a2 |= (__float_as_uint(v.z) >> 31) << cl;
                a3 |= (__float_as_uint(v.w) >> 31) << cl;
            }
            o0 = (u16)(~a0); o1 = (u16)(~a1); o2 = (u16)(~a2); o3 = (u16)(~a3);
        }
        const int wbase = lrow * 56 + col0;
        xb16[(wbase + 0) * 4 + cg] = o0;
        xb16[(wbase + 1) * 4 + cg] = o1;
        xb16[(wbase + 2) * 4 + cg] = o2;
        xb16[(wbase + 3) * 4 + cg] = o3;
    }
    __syncthreads();

    // ---- compute phase: 784 word-tasks (14 rows x 56 cols) over 512 threads
    const u64 w00 = wn[0*8+cw], w01 = wn[1*8+cw], w02 = wn[2*8+cw];
    const u64 w10 = wn[3*8+cw], w11 = wn[4*8+cw], w12 = wn[5*8+cw];
    const u64 w20 = wn[6*8+cw], w21 = wn[7*8+cw], w22 = wn[8*8+cw];

    for (int task = tid; task < 784; task += 512) {
        const int q = task / 56;
        const int c = task - q * 56;
        const int r = r0 + q;
        const int lrow = q + 1;
        const int cm = (c == 0)  ? 0  : c - 1;
        const int cp = (c == 55) ? 55 : c + 1;

        const u64* rT = xb + (lrow - 1) * 56;
        const u64* rM = xb + lrow * 56;
        const u64* rB = xb + (lrow + 1) * 56;
        u64 t0 = rT[cm], t1 = rT[c], t2 = rT[cp];
        u64 m0 = rM[cm], m1 = rM[c], m2 = rM[cp];
        u64 b0 = rB[cm], b1 = rB[c], b2 = rB[cp];

        const u64 mt = (r > 0)  ? ~0ull : 0ull;
        const u64 mb = (r < 55) ? ~0ull : 0ull;
        const u64 ml = (c > 0)  ? ~0ull : 0ull;
        const u64 mr = (c < 55) ? ~0ull : 0ull;

        u64 e0 = (t0 ^ w00) & mt & ml;
        u64 e1 = (t1 ^ w01) & mt;
        u64 e2 = (t2 ^ w02) & mt & mr;
        u64 e3 = (m0 ^ w10) & ml;
        u64 e4 = (m1 ^ w11);
        u64 e5 = (m2 ^ w12) & mr;
        u64 e6 = (b0 ^ w20) & mb & ml;
        u64 e7 = (b1 ^ w21) & mb;
        u64 e8 = (b2 ^ w22) & mb & mr;

        u64 sa, ca, sb, cb, sc, cc, E0, cd, se, ce;
        fa(e0, e1, e2, sa, ca);
        fa(e3, e4, e5, sb, cb);
        fa(e6, e7, e8, sc, cc);
        fa(sa, sb, sc, E0, cd);
        fa(ca, cb, cc, se, ce);
        u64 E1 = se ^ cd, cf = se & cd;
        u64 E2 = ce ^ cf, E3 = ce & cf;

        const int rowe = (r == 0) | (r == 55);
        const int cole = (c == 0) | (c == 55);
        const u64* NTp = NT + (size_t)(rowe + cole) * 40 + (size_t)cw * 5;
        u64 n0 = NTp[0], n1 = NTp[1], n2 = NTp[2], n3 = NTp[3], Fv = NTp[4];

        // carry-out of E + ~T* + 1  ->  (E >= T*)
        u64 cr = E0 | n0;
        cr = (E1 & n1) | (cr & (E1 | n1));
        cr = (E2 & n2) | (cr & (E2 | n2));
        cr = (E3 & n3) | (cr & (E3 | n3));

        s1[(size_t)cw * NPOS + (size_t)b * HW + r * WW + c] = cr ^ Fv;
    }
}

// K2: 1x1 binary conv via XNOR-popcount + BN2 (no LDS; weights via scalar cache)
__global__ __launch_bounds__(256) void pw_kernel(
    const u64* __restrict__ s1, const u64* __restrict__ wbits,
    const float* __restrict__ bn2inv, const float* __restrict__ bn2beta,
    float* __restrict__ out) {
    const int tid = threadIdx.x;
    const int o0  = blockIdx.y * 128;

    const size_t p   = (size_t)blockIdx.x * 256 + tid;
    const int    b   = (int)(p / HW);
    const int    idx = (int)(p - (size_t)b * HW);

    u64 r0 = s1[0u * NPOS + p], r1 = s1[1u * NPOS + p];
    u64 r2 = s1[2u * NPOS + p], r3 = s1[3u * NPOS + p];
    u64 r4 = s1[4u * NPOS + p], r5 = s1[5u * NPOS + p];
    u64 r6 = s1[6u * NPOS + p], r7 = s1[7u * NPOS + p];

    const u64*   wp  = wbits + (size_t)o0 * 8;     // wave-uniform -> s_load
    const float* ivp = bn2inv + o0;
    const float* btp = bn2beta + o0;
    float* outp = out + ((size_t)b * COO + o0) * HW + idx;

    #pragma unroll 4
    for (int ol = 0; ol < 128; ++ol) {
        const u64* w8 = wp + ol * 8;
        int d = __popcll(r0 ^ w8[0]) + __popcll(r1 ^ w8[1])
              + __popcll(r2 ^ w8[2]) + __popcll(r3 ^ w8[3])
              + __popcll(r4 ^ w8[4]) + __popcll(r5 ^ w8[5])
              + __popcll(r6 ^ w8[6]) + __popcll(r7 ^ w8[7]);
        float res = (float)(CC - 2 * d);
        outp[(size_t)ol * HW] = fmaf(res, ivp[ol], btp[ol]);
    }
}

extern "C" void kernel_launch(void* const* d_in, const int* in_sizes, int n_in,
                              void* d_out, int out_size, void* d_ws, size_t ws_size,
                              hipStream_t stream) {
    const float* x    = (const float*)d_in[0];
    const float* w_dw = (const float*)d_in[1];
    const float* w_pw = (const float*)d_in[2];
    const float* g1   = (const float*)d_in[3];
    const float* b1   = (const float*)d_in[4];
    const float* m1   = (const float*)d_in[5];
    const float* v1   = (const float*)d_in[6];
    const float* g2   = (const float*)d_in[7];
    const float* b2   = (const float*)d_in[8];
    const float* m2   = (const float*)d_in[9];
    const float* v2   = (const float*)d_in[10];

    char* ws = (char*)d_ws;
    u64*   s1      = (u64*)(ws + OFF_S1);
    u64*   wbits   = (u64*)(ws + OFF_WBITS);
    u64*   wn      = (u64*)(ws + OFF_WN);
    u64*   NTarr   = (u64*)(ws + OFF_NT);
    float* bn2inv  = (float*)(ws + OFF_BN2INV);
    float* bn2beta = (float*)(ws + OFF_BN2BETA);

    setup_kernel<<<16, 256, 0, stream>>>(w_dw, w_pw, g1, b1, m1, v1, g2, b2, m2, v2,
                                         wbits, wn, NTarr, bn2inv, bn2beta);

    dim3 gf(4, 8, BB);
    dwfused_kernel<<<gf, 512, 0, stream>>>(x, wn, NTarr, s1);

    dim3 g2d(392, 4);
    pw_kernel<<<g2d, 256, 0, stream>>>(s1, wbits, bn2inv, bn2beta, (float*)d_out);
}